// Round 4
// baseline (232.496 us; speedup 1.0000x reference)
//
#include <hip/hip_runtime.h>
#include <hip/hip_bf16.h>

typedef __bf16 bf16x8 __attribute__((ext_vector_type(8)));
typedef __bf16 bf16x4 __attribute__((ext_vector_type(4)));
typedef float  f32x4  __attribute__((ext_vector_type(4)));

#define N_NODES 100000
#define N_EDGES 1000000
#define LATENT  64
#define HID     256
#define RBF_DIM 32
#define NTYPES  10
#define NCHG    6
#define NBOND   5

#define ATOM_TILES (N_NODES / 32)   // 3125
#define ANBLK 512

#define ETILE  64
#define ETILES (N_EDGES / ETILE)    // 15625
#define ENBLK  512

// ---------------------------------------------------------------------------
// prep: q (f32) -> qb (bf16)
// ---------------------------------------------------------------------------
__global__ __launch_bounds__(256) void prep_kernel(
    const float* __restrict__ q, __bf16* __restrict__ qb)
{
    const int i = blockIdx.x * 256 + threadIdx.x;
    const float4 a = *(const float4*)(q + (size_t)i * 8);
    const float4 b = *(const float4*)(q + (size_t)i * 8 + 4);
    bf16x8 v;
    v[0] = (__bf16)a.x; v[1] = (__bf16)a.y; v[2] = (__bf16)a.z; v[3] = (__bf16)a.w;
    v[4] = (__bf16)b.x; v[5] = (__bf16)b.y; v[6] = (__bf16)b.z; v[7] = (__bf16)b.w;
    *(bf16x8*)(qb + (size_t)i * 8) = v;
}

// ---------------------------------------------------------------------------
// Atom MLP via MFMA (unchanged; ~2.5 us)
// ---------------------------------------------------------------------------
struct __align__(16) ASmem {
    __bf16 qs[32][72];
    __bf16 hsE[32][264];
    float  red[4][2][4][64];
};

__global__ __launch_bounds__(256, 2) void atom_kernel(
    const float* __restrict__ q,   const float* __restrict__ aW1,
    const float* __restrict__ ab1, const float* __restrict__ aW2,
    const float* __restrict__ ab2, float* __restrict__ outA,
    float* __restrict__ outB)
{
    __shared__ ASmem sm;
    const int t    = threadIdx.x;
    const int w    = t >> 6;
    const int lane = t & 63;
    const int l15  = lane & 15;
    const int hi   = lane >> 4;
    const int wcol = w * 64;

    bf16x8 aw1f[2][4];
    #pragma unroll
    for (int kb = 0; kb < 2; ++kb)
        #pragma unroll
        for (int nt = 0; nt < 4; ++nt) {
            const int nn = wcol + nt * 16 + l15;
            const int k0 = kb * 32 + hi * 8;
            bf16x8 v;
            #pragma unroll
            for (int j = 0; j < 8; ++j) v[j] = (__bf16)aW1[(k0 + j) * HID + nn];
            aw1f[kb][nt] = v;
        }
    bf16x8 aw2f[2];
    #pragma unroll
    for (int kk = 0; kk < 2; ++kk) {
        const int k0 = (w * 2 + kk) * 32 + hi * 8;
        bf16x8 v;
        #pragma unroll
        for (int j = 0; j < 8; ++j) v[j] = (__bf16)aW2[(k0 + j) * 16 + l15];
        aw2f[kk] = v;
    }
    float4 b1v[4];
    #pragma unroll
    for (int nt = 0; nt < 4; ++nt)
        b1v[nt] = *(const float4*)(&ab1[wcol + nt * 16 + hi * 4]);

    const int m_st = t >> 3;
    const int p_st = t & 7;

    for (int tile = blockIdx.x; tile < ATOM_TILES; tile += ANBLK) {
        const int node0 = tile * 32;
        {
            const float* qr = q + (size_t)(node0 + m_st) * 64 + p_st * 8;
            const float4 a0 = *(const float4*)(qr);
            const float4 a1 = *(const float4*)(qr + 4);
            bf16x8 v;
            v[0] = (__bf16)a0.x; v[1] = (__bf16)a0.y; v[2] = (__bf16)a0.z; v[3] = (__bf16)a0.w;
            v[4] = (__bf16)a1.x; v[5] = (__bf16)a1.y; v[6] = (__bf16)a1.z; v[7] = (__bf16)a1.w;
            *(bf16x8*)(&sm.qs[m_st][p_st * 8]) = v;
        }
        __syncthreads();

        f32x4 acc[2][4];
        #pragma unroll
        for (int mt = 0; mt < 2; ++mt)
            #pragma unroll
            for (int nt = 0; nt < 4; ++nt) {
                f32x4 z = {0.f, 0.f, 0.f, 0.f};
                acc[mt][nt] = z;
            }
        #pragma unroll
        for (int kb = 0; kb < 2; ++kb)
            #pragma unroll
            for (int mt = 0; mt < 2; ++mt) {
                const bf16x8 bq = *(const bf16x8*)((const char*)&sm.qs[0][0]
                                   + (mt * 16 + l15) * 144 + kb * 64 + hi * 16);
                #pragma unroll
                for (int nt = 0; nt < 4; ++nt)
                    acc[mt][nt] = __builtin_amdgcn_mfma_f32_16x16x32_bf16(
                        aw1f[kb][nt], bq, acc[mt][nt], 0, 0, 0);
            }
        #pragma unroll
        for (int mt = 0; mt < 2; ++mt)
            #pragma unroll
            for (int nt = 0; nt < 4; ++nt) {
                bf16x4 hv;
                #pragma unroll
                for (int r = 0; r < 4; ++r)
                    hv[r] = (__bf16)fmaxf(acc[mt][nt][r] + ((const float*)&b1v[nt])[r], 0.f);
                *(bf16x4*)(&sm.hsE[mt * 16 + l15][wcol + nt * 16 + hi * 4]) = hv;
            }
        __syncthreads();

        f32x4 acc2[2];
        {
            f32x4 z = {0.f, 0.f, 0.f, 0.f};
            acc2[0] = z; acc2[1] = z;
        }
        #pragma unroll
        for (int mt = 0; mt < 2; ++mt)
            #pragma unroll
            for (int kk = 0; kk < 2; ++kk) {
                const int kb = w * 2 + kk;
                const bf16x8 af = *(const bf16x8*)((const char*)&sm.hsE[0][0]
                                   + (mt * 16 + l15) * 528 + kb * 64 + hi * 16);
                acc2[mt] = __builtin_amdgcn_mfma_f32_16x16x32_bf16(
                    af, aw2f[kk], acc2[mt], 0, 0, 0);
            }
        #pragma unroll
        for (int mt = 0; mt < 2; ++mt)
            #pragma unroll
            for (int r = 0; r < 4; ++r)
                sm.red[w][mt][r][lane] = acc2[mt][r];
        __syncthreads();

        {
            const int o  = t & 15;
            const int m0 = t >> 4;
            #pragma unroll
            for (int half = 0; half < 2; ++half) {
                const int m  = m0 + half * 16;
                const int mt = m >> 4, rr = m & 15;
                const int hh = rr >> 2, r = rr & 3;
                float s = ab2[o];
                #pragma unroll
                for (int ww = 0; ww < 4; ++ww) s += sm.red[ww][mt][r][hh * 16 + o];
                const int node = node0 + m;
                if (o < NTYPES) outA[node * NTYPES + o] = s;
                else            outB[node * NCHG + (o - NTYPES)] = s;
            }
        }
        __syncthreads();
    }
}

// ---------------------------------------------------------------------------
// Edge MLP v4: 64-edge tiles, 8 waves as 2(edge)x4(hidden) grid.
// Wave = 64 hidden x 32 edges (halves comb broadcast re-reads).
// T2 XOR-swizzled LDS (power-of-2 row strides, byte ^= (row&7)<<4).
// Raw s_barrier + lgkmcnt(0) so prefetch gathers stay in flight.
// ---------------------------------------------------------------------------
struct __align__(16) ESmem {
    __bf16 comb[ETILE][128];   // 16384 B, 256 B rows (cols 0..95 used)
    __bf16 hsE[ETILE][256];    // 32768 B, 512 B rows
    __bf16 w2t[16][256];       // 8192 B,  512 B rows
};                             // 57344 B

__device__ __forceinline__ void bar_lgkm() {
    asm volatile("s_waitcnt lgkmcnt(0)" ::: "memory");
    __builtin_amdgcn_s_barrier();
}

template<bool USEBF>
__global__ __launch_bounds__(512, 4) void edge_kernel(
    const float* __restrict__ pos, const float* __restrict__ qf,
    const __bf16* __restrict__ qb, const int* __restrict__ pair,
    const float* __restrict__ bW1, const float* __restrict__ bb1,
    const float* __restrict__ bW2, const float* __restrict__ bb2,
    float* __restrict__ outC)
{
    __shared__ ESmem sm;
    const int t    = threadIdx.x;
    const int w    = t >> 6;
    const int lane = t & 63;
    const int l15  = lane & 15;
    const int hi   = lane >> 4;
    const int hid0 = (w & 3) * 64;     // ng*64 : wave's hidden base
    const int emg  = (w >> 2) * 32;    // mg*32 : wave's edge base
    const int swz  = (l15 & 7) << 4;   // XOR swizzle for rows == l15 (mod 8)

    // one-time: W2 (padded to 16 out-cols) transposed into LDS [o][k], swizzled
    {
        const int o  = t >> 5;          // 0..15
        const int kq = t & 31;          // octet index
        bf16x8 v;
        #pragma unroll
        for (int j = 0; j < 8; ++j)
            v[j] = (o < NBOND) ? (__bf16)bW2[(kq * 8 + j) * NBOND + o] : (__bf16)0.f;
        *(bf16x8*)((char*)&sm.w2t[0][0] + o * 512 + ((kq * 16) ^ ((o & 7) << 4))) = v;
    }

    // per-block constants: W1^T fragments for this wave's 64 hidden cols
    bf16x8 bw1f[3][4];
    #pragma unroll
    for (int kb = 0; kb < 3; ++kb)
        #pragma unroll
        for (int nt = 0; nt < 4; ++nt) {
            const int nn = hid0 + nt * 16 + l15;
            const int k0 = kb * 32 + hi * 8;
            bf16x8 v;
            #pragma unroll
            for (int j = 0; j < 8; ++j) v[j] = (__bf16)bW1[(k0 + j) * HID + nn];
            bw1f[kb][nt] = v;
        }
    float4 b1v[4];
    #pragma unroll
    for (int nt = 0; nt < 4; ++nt)
        b1v[nt] = *(const float4*)(&bb1[hid0 + nt * 16 + hi * 4]);
    const float bb2v = (l15 < NBOND) ? bb2[l15] : 0.f;

    const int e_loc = t >> 3;   // 0..63 staging edge slot
    const int p     = t & 7;    // 8 threads/edge
    const int wswz  = (e_loc & 7) << 4;

    // ---- prefetch state ----
    int tile = blockIdx.x;
    int2 pA = ((const int2*)pair)[(size_t)tile * ETILE + e_loc];
    bf16x8 gs, gd;
    float4 fs0, fs1, fd0, fd1;
    float  ps0, ps1, ps2, pd0, pd1, pd2;
    if constexpr (USEBF) {
        gs = *(const bf16x8*)(qb + (size_t)pA.x * 64 + p * 8);
        gd = *(const bf16x8*)(qb + (size_t)pA.y * 64 + p * 8);
    } else {
        fs0 = *(const float4*)(qf + (size_t)pA.x * 64 + p * 8);
        fs1 = *(const float4*)(qf + (size_t)pA.x * 64 + p * 8 + 4);
        fd0 = *(const float4*)(qf + (size_t)pA.y * 64 + p * 8);
        fd1 = *(const float4*)(qf + (size_t)pA.y * 64 + p * 8 + 4);
    }
    ps0 = pos[(size_t)pA.x * 3];  ps1 = pos[(size_t)pA.x * 3 + 1];  ps2 = pos[(size_t)pA.x * 3 + 2];
    pd0 = pos[(size_t)pA.y * 3];  pd1 = pos[(size_t)pA.y * 3 + 1];  pd2 = pos[(size_t)pA.y * 3 + 2];
    {
        const int tn = tile + ENBLK;
        pA = ((const int2*)pair)[(tn < ETILES ? (size_t)tn * ETILE : 0) + e_loc];
    }
    __syncthreads();   // w2t visible

    for (; tile < ETILES; tile += ENBLK) {
        const int e0 = tile * ETILE;

        // ---- stage comb(tile) from prefetched regs (swizzled writes) ----
        {
            bf16x8 cv;
            if constexpr (USEBF) {
                #pragma unroll
                for (int j = 0; j < 8; ++j)
                    cv[j] = (__bf16)((float)gs[j] + (float)gd[j]);
            } else {
                cv[0] = (__bf16)(fs0.x + fd0.x); cv[1] = (__bf16)(fs0.y + fd0.y);
                cv[2] = (__bf16)(fs0.z + fd0.z); cv[3] = (__bf16)(fs0.w + fd0.w);
                cv[4] = (__bf16)(fs1.x + fd1.x); cv[5] = (__bf16)(fs1.y + fd1.y);
                cv[6] = (__bf16)(fs1.z + fd1.z); cv[7] = (__bf16)(fs1.w + fd1.w);
            }
            *(bf16x8*)((char*)&sm.comb[0][0] + e_loc * 256 + ((p * 16) ^ wswz)) = cv;

            const float dx = ps0 - pd0, dy = ps1 - pd1, dz = ps2 - pd2;
            const float D  = sqrtf(fmaxf(dx * dx + dy * dy + dz * dz, 1e-8f));
            bf16x4 rv;
            #pragma unroll
            for (int j = 0; j < 4; ++j) {
                const float mu = (float)(p * 4 + j) * (10.0f / 31.0f);
                const float z  = (D - mu) * 3.2f;
                rv[j] = (__bf16)__expf(-z * z);
            }
            *(bf16x4*)((char*)&sm.comb[0][0] + e_loc * 256 + ((128 + p * 8) ^ wswz)) = rv;
        }

        // ---- issue prefetch for tile+ENBLK (rides across barriers) ----
        {
            const int2 pN = pA;
            if constexpr (USEBF) {
                gs = *(const bf16x8*)(qb + (size_t)pN.x * 64 + p * 8);
                gd = *(const bf16x8*)(qb + (size_t)pN.y * 64 + p * 8);
            } else {
                fs0 = *(const float4*)(qf + (size_t)pN.x * 64 + p * 8);
                fs1 = *(const float4*)(qf + (size_t)pN.x * 64 + p * 8 + 4);
                fd0 = *(const float4*)(qf + (size_t)pN.y * 64 + p * 8);
                fd1 = *(const float4*)(qf + (size_t)pN.y * 64 + p * 8 + 4);
            }
            ps0 = pos[(size_t)pN.x * 3];  ps1 = pos[(size_t)pN.x * 3 + 1];  ps2 = pos[(size_t)pN.x * 3 + 2];
            pd0 = pos[(size_t)pN.y * 3];  pd1 = pos[(size_t)pN.y * 3 + 1];  pd2 = pos[(size_t)pN.y * 3 + 2];
            const int tnn = tile + 2 * ENBLK;
            pA = ((const int2*)pair)[(tnn < ETILES ? (size_t)tnn * ETILE : 0) + e_loc];
        }
        bar_lgkm();   // bar1: comb ready (prefetch stays in flight)

        // ---- layer 1: wave computes [64 hidden x 32 edges] ----
        f32x4 acc[2][4];
        #pragma unroll
        for (int mt = 0; mt < 2; ++mt)
            #pragma unroll
            for (int nt = 0; nt < 4; ++nt) {
                f32x4 z = {0.f, 0.f, 0.f, 0.f};
                acc[mt][nt] = z;
            }
        #pragma unroll
        for (int kb = 0; kb < 3; ++kb)
            #pragma unroll
            for (int mt = 0; mt < 2; ++mt) {
                const bf16x8 bf = *(const bf16x8*)((const char*)&sm.comb[0][0]
                                   + (emg + mt * 16 + l15) * 256
                                   + ((kb * 64 + hi * 16) ^ swz));
                #pragma unroll
                for (int nt = 0; nt < 4; ++nt)
                    acc[mt][nt] = __builtin_amdgcn_mfma_f32_16x16x32_bf16(
                        bw1f[kb][nt], bf, acc[mt][nt], 0, 0, 0);
            }
        // relu + bias -> hsE[edge][hidden] (swizzled b64 stores)
        #pragma unroll
        for (int mt = 0; mt < 2; ++mt)
            #pragma unroll
            for (int nt = 0; nt < 4; ++nt) {
                bf16x4 hv;
                #pragma unroll
                for (int r = 0; r < 4; ++r)
                    hv[r] = (__bf16)fmaxf(acc[mt][nt][r] + ((const float*)&b1v[nt])[r], 0.f);
                *(bf16x4*)((char*)&sm.hsE[0][0]
                           + (emg + mt * 16 + l15) * 512
                           + ((hid0 * 2 + nt * 32 + hi * 8) ^ swz)) = hv;
            }
        bar_lgkm();   // bar2: hsE ready (prefetch still in flight)

        // ---- layer 2: waves 0-3 (edge-group w), full K, direct store ----
        if (w < 4) {
            f32x4 a2a = {0.f, 0.f, 0.f, 0.f};
            f32x4 a2b = {0.f, 0.f, 0.f, 0.f};
            #pragma unroll
            for (int kk = 0; kk < 8; kk += 2) {
                const bf16x8 af0 = *(const bf16x8*)((const char*)&sm.hsE[0][0]
                                    + (w * 16 + l15) * 512 + ((kk * 64 + hi * 16) ^ swz));
                const bf16x8 bf0 = *(const bf16x8*)((const char*)&sm.w2t[0][0]
                                    + l15 * 512 + ((kk * 64 + hi * 16) ^ swz));
                a2a = __builtin_amdgcn_mfma_f32_16x16x32_bf16(af0, bf0, a2a, 0, 0, 0);
                const bf16x8 af1 = *(const bf16x8*)((const char*)&sm.hsE[0][0]
                                    + (w * 16 + l15) * 512 + (((kk + 1) * 64 + hi * 16) ^ swz));
                const bf16x8 bf1 = *(const bf16x8*)((const char*)&sm.w2t[0][0]
                                    + l15 * 512 + (((kk + 1) * 64 + hi * 16) ^ swz));
                a2b = __builtin_amdgcn_mfma_f32_16x16x32_bf16(af1, bf1, a2b, 0, 0, 0);
            }
            if (l15 < NBOND) {
                #pragma unroll
                for (int r = 0; r < 4; ++r)
                    outC[(size_t)(e0 + w * 16 + hi * 4 + r) * NBOND + l15]
                        = a2a[r] + a2b[r] + bb2v;
            }
        }
    }
}

// ---------------------------------------------------------------------------
extern "C" void kernel_launch(void* const* d_in, const int* in_sizes, int n_in,
                              void* d_out, int out_size, void* d_ws, size_t ws_size,
                              hipStream_t stream)
{
    const float* pos = (const float*)d_in[0];
    const float* q   = (const float*)d_in[1];
    const int*   pair= (const int*)  d_in[2];
    const float* aW1 = (const float*)d_in[3];
    const float* ab1 = (const float*)d_in[4];
    const float* aW2 = (const float*)d_in[5];
    const float* ab2 = (const float*)d_in[6];
    const float* bW1 = (const float*)d_in[7];
    const float* bb1 = (const float*)d_in[8];
    const float* bW2 = (const float*)d_in[9];
    const float* bb2 = (const float*)d_in[10];

    float* out  = (float*)d_out;
    float* outA = out;
    float* outB = out + (size_t)N_NODES * NTYPES;
    float* outC = out + (size_t)N_NODES * (NTYPES + NCHG);

    const size_t qb_bytes = (size_t)N_NODES * LATENT * sizeof(__bf16);
    const bool use_bf = (ws_size >= qb_bytes);
    __bf16* qb = (__bf16*)d_ws;

    if (use_bf)
        hipLaunchKernelGGL(prep_kernel, dim3(N_NODES * LATENT / (256 * 8)), dim3(256),
                           0, stream, q, qb);

    hipLaunchKernelGGL(atom_kernel, dim3(ANBLK), dim3(256), 0, stream,
                       q, aW1, ab1, aW2, ab2, outA, outB);

    if (use_bf)
        hipLaunchKernelGGL(edge_kernel<true>, dim3(ENBLK), dim3(512), 0, stream,
                           pos, q, qb, pair, bW1, bb1, bW2, bb2, outC);
    else
        hipLaunchKernelGGL(edge_kernel<false>, dim3(ENBLK), dim3(512), 0, stream,
                           pos, q, qb, pair, bW1, bb1, bW2, bb2, outC);
}

// Round 5
// 98.991 us; speedup vs baseline: 2.3487x; 2.3487x over previous
//
#include <hip/hip_runtime.h>
#include <hip/hip_bf16.h>

typedef __bf16 bf16x8 __attribute__((ext_vector_type(8)));
typedef __bf16 bf16x4 __attribute__((ext_vector_type(4)));
typedef float  f32x4  __attribute__((ext_vector_type(4)));

#define N_NODES 100000
#define N_EDGES 1000000
#define LATENT  64
#define HID     256
#define RBF_DIM 32
#define NTYPES  10
#define NCHG    6
#define NBOND   5

#define ATOM_TILES (N_NODES / 32)   // 3125
#define ANBLK 512

#define ETILE  64
#define ETILES (N_EDGES / ETILE)    // 15625
#define ENBLK  512

// ---------------------------------------------------------------------------
// Atom MLP via MFMA; also emits qb = bf16(q) (prep fused in).
// ---------------------------------------------------------------------------
struct __align__(16) ASmem {
    __bf16 qs[32][72];
    __bf16 hsE[32][264];
    float  red[4][2][4][64];
};

template<bool EMIT_QB>
__global__ __launch_bounds__(256, 2) void atom_kernel(
    const float* __restrict__ q,   const float* __restrict__ aW1,
    const float* __restrict__ ab1, const float* __restrict__ aW2,
    const float* __restrict__ ab2, float* __restrict__ outA,
    float* __restrict__ outB,      __bf16* __restrict__ qb)
{
    __shared__ ASmem sm;
    const int t    = threadIdx.x;
    const int w    = t >> 6;
    const int lane = t & 63;
    const int l15  = lane & 15;
    const int hi   = lane >> 4;
    const int wcol = w * 64;

    bf16x8 aw1f[2][4];
    #pragma unroll
    for (int kb = 0; kb < 2; ++kb)
        #pragma unroll
        for (int nt = 0; nt < 4; ++nt) {
            const int nn = wcol + nt * 16 + l15;
            const int k0 = kb * 32 + hi * 8;
            bf16x8 v;
            #pragma unroll
            for (int j = 0; j < 8; ++j) v[j] = (__bf16)aW1[(k0 + j) * HID + nn];
            aw1f[kb][nt] = v;
        }
    bf16x8 aw2f[2];
    #pragma unroll
    for (int kk = 0; kk < 2; ++kk) {
        const int k0 = (w * 2 + kk) * 32 + hi * 8;
        bf16x8 v;
        #pragma unroll
        for (int j = 0; j < 8; ++j) v[j] = (__bf16)aW2[(k0 + j) * 16 + l15];
        aw2f[kk] = v;
    }
    float4 b1v[4];
    #pragma unroll
    for (int nt = 0; nt < 4; ++nt)
        b1v[nt] = *(const float4*)(&ab1[wcol + nt * 16 + hi * 4]);

    const int m_st = t >> 3;
    const int p_st = t & 7;

    for (int tile = blockIdx.x; tile < ATOM_TILES; tile += ANBLK) {
        const int node0 = tile * 32;
        {
            const float* qr = q + (size_t)(node0 + m_st) * 64 + p_st * 8;
            const float4 a0 = *(const float4*)(qr);
            const float4 a1 = *(const float4*)(qr + 4);
            bf16x8 v;
            v[0] = (__bf16)a0.x; v[1] = (__bf16)a0.y; v[2] = (__bf16)a0.z; v[3] = (__bf16)a0.w;
            v[4] = (__bf16)a1.x; v[5] = (__bf16)a1.y; v[6] = (__bf16)a1.z; v[7] = (__bf16)a1.w;
            *(bf16x8*)(&sm.qs[m_st][p_st * 8]) = v;
            if constexpr (EMIT_QB)
                *(bf16x8*)(qb + (size_t)(node0 + m_st) * 64 + p_st * 8) = v;
        }
        __syncthreads();

        // layer 1: acc pre-loaded with bias (saves the epilogue add)
        f32x4 acc[2][4];
        #pragma unroll
        for (int mt = 0; mt < 2; ++mt)
            #pragma unroll
            for (int nt = 0; nt < 4; ++nt)
                #pragma unroll
                for (int r = 0; r < 4; ++r)
                    acc[mt][nt][r] = ((const float*)&b1v[nt])[r];

        __builtin_amdgcn_s_setprio(1);
        #pragma unroll
        for (int kb = 0; kb < 2; ++kb)
            #pragma unroll
            for (int mt = 0; mt < 2; ++mt) {
                const bf16x8 bq = *(const bf16x8*)((const char*)&sm.qs[0][0]
                                   + (mt * 16 + l15) * 144 + kb * 64 + hi * 16);
                #pragma unroll
                for (int nt = 0; nt < 4; ++nt)
                    acc[mt][nt] = __builtin_amdgcn_mfma_f32_16x16x32_bf16(
                        aw1f[kb][nt], bq, acc[mt][nt], 0, 0, 0);
            }
        __builtin_amdgcn_s_setprio(0);

        #pragma unroll
        for (int mt = 0; mt < 2; ++mt)
            #pragma unroll
            for (int nt = 0; nt < 4; ++nt) {
                bf16x4 hv;
                #pragma unroll
                for (int r = 0; r < 4; ++r)
                    hv[r] = (__bf16)fmaxf(acc[mt][nt][r], 0.f);
                *(bf16x4*)(&sm.hsE[mt * 16 + l15][wcol + nt * 16 + hi * 4]) = hv;
            }
        __syncthreads();

        f32x4 acc2[2];
        {
            f32x4 z = {0.f, 0.f, 0.f, 0.f};
            acc2[0] = z; acc2[1] = z;
        }
        __builtin_amdgcn_s_setprio(1);
        #pragma unroll
        for (int mt = 0; mt < 2; ++mt)
            #pragma unroll
            for (int kk = 0; kk < 2; ++kk) {
                const int kb = w * 2 + kk;
                const bf16x8 af = *(const bf16x8*)((const char*)&sm.hsE[0][0]
                                   + (mt * 16 + l15) * 528 + kb * 64 + hi * 16);
                acc2[mt] = __builtin_amdgcn_mfma_f32_16x16x32_bf16(
                    af, aw2f[kk], acc2[mt], 0, 0, 0);
            }
        __builtin_amdgcn_s_setprio(0);
        #pragma unroll
        for (int mt = 0; mt < 2; ++mt)
            #pragma unroll
            for (int r = 0; r < 4; ++r)
                sm.red[w][mt][r][lane] = acc2[mt][r];
        __syncthreads();

        {
            const int o  = t & 15;
            const int m0 = t >> 4;
            #pragma unroll
            for (int half = 0; half < 2; ++half) {
                const int m  = m0 + half * 16;
                const int mt = m >> 4, rr = m & 15;
                const int hh = rr >> 2, r = rr & 3;
                float s = ab2[o];
                #pragma unroll
                for (int ww = 0; ww < 4; ++ww) s += sm.red[ww][mt][r][hh * 16 + o];
                const int node = node0 + m;
                if (o < NTYPES) outA[node * NTYPES + o] = s;
                else            outB[node * NCHG + (o - NTYPES)] = s;
            }
        }
        __syncthreads();
    }
}

// ---------------------------------------------------------------------------
// Edge MLP v5 = proven v3 structure (92us) + {bias-in-acc init, lgkm-only
// barriers, setprio around MFMA, 32-bit gather offsets}.
// 64-edge tiles, 8 waves (N-split: 32 hidden/wave), 2 barriers/tile,
// prefetch pair 2 ahead / gathers 1 ahead.
// ---------------------------------------------------------------------------
struct __align__(16) ESmem {
    __bf16 comb[ETILE][104];   // 13312 B (208 B rows: bank-spread, measured ok)
    __bf16 hsE[ETILE][264];    // 33792 B (528 B rows)
    __bf16 w2t[16][264];       // 8448 B
};                             // 55552 B

__device__ __forceinline__ void bar_lgkm() {
    asm volatile("s_waitcnt lgkmcnt(0)" ::: "memory");
    __builtin_amdgcn_s_barrier();
}

template<bool USEBF>
__global__ __launch_bounds__(512, 4) void edge_kernel(
    const float* __restrict__ pos, const float* __restrict__ qf,
    const __bf16* __restrict__ qb, const int* __restrict__ pair,
    const float* __restrict__ bW1, const float* __restrict__ bb1,
    const float* __restrict__ bW2, const float* __restrict__ bb2,
    float* __restrict__ outC)
{
    __shared__ ESmem sm;
    const int t    = threadIdx.x;
    const int w    = t >> 6;
    const int lane = t & 63;
    const int l15  = lane & 15;
    const int hi   = lane >> 4;
    const int wcol = w * 32;

    // one-time: W2 (padded to 16 out-cols) transposed into LDS [o][k]
    {
        const int o  = t >> 5;
        const int k0 = (t & 31) * 8;
        bf16x8 v;
        #pragma unroll
        for (int j = 0; j < 8; ++j)
            v[j] = (o < NBOND) ? (__bf16)bW2[(k0 + j) * NBOND + o] : (__bf16)0.f;
        *(bf16x8*)(&sm.w2t[o][k0]) = v;
    }

    bf16x8 bw1f[3][2];
    #pragma unroll
    for (int kb = 0; kb < 3; ++kb)
        #pragma unroll
        for (int nt = 0; nt < 2; ++nt) {
            const int nn = wcol + nt * 16 + l15;
            const int k0 = kb * 32 + hi * 8;
            bf16x8 v;
            #pragma unroll
            for (int j = 0; j < 8; ++j) v[j] = (__bf16)bW1[(k0 + j) * HID + nn];
            bw1f[kb][nt] = v;
        }
    float4 b1v[2];
    b1v[0] = *(const float4*)(&bb1[wcol + hi * 4]);
    b1v[1] = *(const float4*)(&bb1[wcol + 16 + hi * 4]);
    const float bb2v = (l15 < NBOND) ? bb2[l15] : 0.f;

    const int e_loc = t >> 3;
    const int p     = t & 7;

    // ---- prefetch state (32-bit offsets) ----
    int tile = blockIdx.x;
    int2 pA = ((const int2*)pair)[(size_t)tile * ETILE + e_loc];
    bf16x8 gs, gd;
    float4 fs0, fs1, fd0, fd1;
    float  ps0, ps1, ps2, pd0, pd1, pd2;
    if constexpr (USEBF) {
        gs = *(const bf16x8*)(qb + ((unsigned)pA.x * 64u + (unsigned)(p * 8)));
        gd = *(const bf16x8*)(qb + ((unsigned)pA.y * 64u + (unsigned)(p * 8)));
    } else {
        fs0 = *(const float4*)(qf + ((unsigned)pA.x * 64u + (unsigned)(p * 8)));
        fs1 = *(const float4*)(qf + ((unsigned)pA.x * 64u + (unsigned)(p * 8) + 4u));
        fd0 = *(const float4*)(qf + ((unsigned)pA.y * 64u + (unsigned)(p * 8)));
        fd1 = *(const float4*)(qf + ((unsigned)pA.y * 64u + (unsigned)(p * 8) + 4u));
    }
    ps0 = pos[(unsigned)pA.x * 3u];  ps1 = pos[(unsigned)pA.x * 3u + 1u];  ps2 = pos[(unsigned)pA.x * 3u + 2u];
    pd0 = pos[(unsigned)pA.y * 3u];  pd1 = pos[(unsigned)pA.y * 3u + 1u];  pd2 = pos[(unsigned)pA.y * 3u + 2u];
    {
        const int tn = tile + ENBLK;
        pA = ((const int2*)pair)[(tn < ETILES ? (size_t)tn * ETILE : 0) + e_loc];
    }
    __syncthreads();   // w2t visible

    for (; tile < ETILES; tile += ENBLK) {
        const int e0 = tile * ETILE;

        // ---- stage comb(tile) from prefetched regs ----
        {
            bf16x8 cv;
            if constexpr (USEBF) {
                #pragma unroll
                for (int j = 0; j < 8; ++j)
                    cv[j] = (__bf16)((float)gs[j] + (float)gd[j]);
            } else {
                cv[0] = (__bf16)(fs0.x + fd0.x); cv[1] = (__bf16)(fs0.y + fd0.y);
                cv[2] = (__bf16)(fs0.z + fd0.z); cv[3] = (__bf16)(fs0.w + fd0.w);
                cv[4] = (__bf16)(fs1.x + fd1.x); cv[5] = (__bf16)(fs1.y + fd1.y);
                cv[6] = (__bf16)(fs1.z + fd1.z); cv[7] = (__bf16)(fs1.w + fd1.w);
            }
            *(bf16x8*)(&sm.comb[e_loc][p * 8]) = cv;

            const float dx = ps0 - pd0, dy = ps1 - pd1, dz = ps2 - pd2;
            const float D  = sqrtf(fmaxf(dx * dx + dy * dy + dz * dz, 1e-8f));
            bf16x4 rv;
            #pragma unroll
            for (int j = 0; j < 4; ++j) {
                const float mu = (float)(p * 4 + j) * (10.0f / 31.0f);
                const float z  = (D - mu) * 3.2f;
                rv[j] = (__bf16)__expf(-z * z);
            }
            *(bf16x4*)(&sm.comb[e_loc][64 + p * 4]) = rv;
        }

        // ---- issue prefetch for tile+ENBLK (rides across barriers) ----
        {
            const int2 pN = pA;
            if constexpr (USEBF) {
                gs = *(const bf16x8*)(qb + ((unsigned)pN.x * 64u + (unsigned)(p * 8)));
                gd = *(const bf16x8*)(qb + ((unsigned)pN.y * 64u + (unsigned)(p * 8)));
            } else {
                fs0 = *(const float4*)(qf + ((unsigned)pN.x * 64u + (unsigned)(p * 8)));
                fs1 = *(const float4*)(qf + ((unsigned)pN.x * 64u + (unsigned)(p * 8) + 4u));
                fd0 = *(const float4*)(qf + ((unsigned)pN.y * 64u + (unsigned)(p * 8)));
                fd1 = *(const float4*)(qf + ((unsigned)pN.y * 64u + (unsigned)(p * 8) + 4u));
            }
            ps0 = pos[(unsigned)pN.x * 3u];  ps1 = pos[(unsigned)pN.x * 3u + 1u];  ps2 = pos[(unsigned)pN.x * 3u + 2u];
            pd0 = pos[(unsigned)pN.y * 3u];  pd1 = pos[(unsigned)pN.y * 3u + 1u];  pd2 = pos[(unsigned)pN.y * 3u + 2u];
            const int tnn = tile + 2 * ENBLK;
            pA = ((const int2*)pair)[(tnn < ETILES ? (size_t)tnn * ETILE : 0) + e_loc];
        }
        bar_lgkm();   // bar1: comb ready (gathers stay in flight)

        // ---- layer 1: wave owns 32 hidden x 64 edges; acc = bias ----
        f32x4 acc[4][2];
        #pragma unroll
        for (int mt = 0; mt < 4; ++mt)
            #pragma unroll
            for (int nt = 0; nt < 2; ++nt)
                #pragma unroll
                for (int r = 0; r < 4; ++r)
                    acc[mt][nt][r] = ((const float*)&b1v[nt])[r];

        __builtin_amdgcn_s_setprio(1);
        #pragma unroll
        for (int kb = 0; kb < 3; ++kb)
            #pragma unroll
            for (int mt = 0; mt < 4; ++mt) {
                const bf16x8 bf = *(const bf16x8*)((const char*)&sm.comb[0][0]
                                   + (mt * 16 + l15) * 208 + kb * 64 + hi * 16);
                acc[mt][0] = __builtin_amdgcn_mfma_f32_16x16x32_bf16(
                    bw1f[kb][0], bf, acc[mt][0], 0, 0, 0);
                acc[mt][1] = __builtin_amdgcn_mfma_f32_16x16x32_bf16(
                    bw1f[kb][1], bf, acc[mt][1], 0, 0, 0);
            }
        __builtin_amdgcn_s_setprio(0);

        // relu -> hsE[edge][hidden]
        #pragma unroll
        for (int mt = 0; mt < 4; ++mt)
            #pragma unroll
            for (int nt = 0; nt < 2; ++nt) {
                bf16x4 hv;
                #pragma unroll
                for (int r = 0; r < 4; ++r)
                    hv[r] = (__bf16)fmaxf(acc[mt][nt][r], 0.f);
                *(bf16x4*)((char*)&sm.hsE[0][0]
                           + (mt * 16 + l15) * 528 + (wcol + nt * 16 + hi * 4) * 2) = hv;
            }
        bar_lgkm();   // bar2: hsE ready

        // ---- layer 2: waves 0-3, M-split, full K, direct store ----
        if (w < 4) {
            f32x4 a2a, a2b;
            #pragma unroll
            for (int r = 0; r < 4; ++r) { a2a[r] = bb2v; a2b[r] = 0.f; }
            __builtin_amdgcn_s_setprio(1);
            #pragma unroll
            for (int kk = 0; kk < 8; kk += 2) {
                const bf16x8 af0 = *(const bf16x8*)((const char*)&sm.hsE[0][0]
                                    + (w * 16 + l15) * 528 + kk * 64 + hi * 16);
                const bf16x8 bf0 = *(const bf16x8*)((const char*)&sm.w2t[0][0]
                                    + l15 * 528 + kk * 64 + hi * 16);
                a2a = __builtin_amdgcn_mfma_f32_16x16x32_bf16(af0, bf0, a2a, 0, 0, 0);
                const bf16x8 af1 = *(const bf16x8*)((const char*)&sm.hsE[0][0]
                                    + (w * 16 + l15) * 528 + (kk + 1) * 64 + hi * 16);
                const bf16x8 bf1 = *(const bf16x8*)((const char*)&sm.w2t[0][0]
                                    + l15 * 528 + (kk + 1) * 64 + hi * 16);
                a2b = __builtin_amdgcn_mfma_f32_16x16x32_bf16(af1, bf1, a2b, 0, 0, 0);
            }
            __builtin_amdgcn_s_setprio(0);
            if (l15 < NBOND) {
                #pragma unroll
                for (int r = 0; r < 4; ++r)
                    outC[(size_t)(e0 + w * 16 + hi * 4 + r) * NBOND + l15]
                        = a2a[r] + a2b[r];
            }
        }
    }
}

// ---------------------------------------------------------------------------
extern "C" void kernel_launch(void* const* d_in, const int* in_sizes, int n_in,
                              void* d_out, int out_size, void* d_ws, size_t ws_size,
                              hipStream_t stream)
{
    const float* pos = (const float*)d_in[0];
    const float* q   = (const float*)d_in[1];
    const int*   pair= (const int*)  d_in[2];
    const float* aW1 = (const float*)d_in[3];
    const float* ab1 = (const float*)d_in[4];
    const float* aW2 = (const float*)d_in[5];
    const float* ab2 = (const float*)d_in[6];
    const float* bW1 = (const float*)d_in[7];
    const float* bb1 = (const float*)d_in[8];
    const float* bW2 = (const float*)d_in[9];
    const float* bb2 = (const float*)d_in[10];

    float* out  = (float*)d_out;
    float* outA = out;
    float* outB = out + (size_t)N_NODES * NTYPES;
    float* outC = out + (size_t)N_NODES * (NTYPES + NCHG);

    const size_t qb_bytes = (size_t)N_NODES * LATENT * sizeof(__bf16);
    const bool use_bf = (ws_size >= qb_bytes);
    __bf16* qb = (__bf16*)d_ws;

    if (use_bf)
        hipLaunchKernelGGL(atom_kernel<true>, dim3(ANBLK), dim3(256), 0, stream,
                           q, aW1, ab1, aW2, ab2, outA, outB, qb);
    else
        hipLaunchKernelGGL(atom_kernel<false>, dim3(ANBLK), dim3(256), 0, stream,
                           q, aW1, ab1, aW2, ab2, outA, outB, qb);

    if (use_bf)
        hipLaunchKernelGGL(edge_kernel<true>, dim3(ENBLK), dim3(512), 0, stream,
                           pos, q, qb, pair, bW1, bb1, bW2, bb2, outC);
    else
        hipLaunchKernelGGL(edge_kernel<false>, dim3(ENBLK), dim3(512), 0, stream,
                           pos, q, qb, pair, bW1, bb1, bW2, bb2, outC);
}

// Round 6
// 98.880 us; speedup vs baseline: 2.3513x; 1.0011x over previous
//
#include <hip/hip_runtime.h>
#include <hip/hip_bf16.h>

typedef __bf16 bf16x8 __attribute__((ext_vector_type(8)));
typedef __bf16 bf16x4 __attribute__((ext_vector_type(4)));
typedef float  f32x4  __attribute__((ext_vector_type(4)));

#define N_NODES 100000
#define N_EDGES 1000000
#define LATENT  64
#define HID     256
#define RBF_DIM 32
#define NTYPES  10
#define NCHG    6
#define NBOND   5

#define ATOM_TILES (N_NODES / 32)   // 3125
#define ANBLK 512

#define ETILE  32
#define ETILES (N_EDGES / ETILE)    // 31250
#define ENBLK  768                  // 3 blocks/CU x 256 CUs

// ---------------------------------------------------------------------------
// Atom MLP via MFMA; also emits qb = bf16(q). (~2.5 us, proven)
// ---------------------------------------------------------------------------
struct __align__(16) ASmem {
    __bf16 qs[32][72];
    __bf16 hsE[32][264];
    float  red[4][2][4][64];
};

template<bool EMIT_QB>
__global__ __launch_bounds__(256, 2) void atom_kernel(
    const float* __restrict__ q,   const float* __restrict__ aW1,
    const float* __restrict__ ab1, const float* __restrict__ aW2,
    const float* __restrict__ ab2, float* __restrict__ outA,
    float* __restrict__ outB,      __bf16* __restrict__ qb)
{
    __shared__ ASmem sm;
    const int t    = threadIdx.x;
    const int w    = t >> 6;
    const int lane = t & 63;
    const int l15  = lane & 15;
    const int hi   = lane >> 4;
    const int wcol = w * 64;

    bf16x8 aw1f[2][4];
    #pragma unroll
    for (int kb = 0; kb < 2; ++kb)
        #pragma unroll
        for (int nt = 0; nt < 4; ++nt) {
            const int nn = wcol + nt * 16 + l15;
            const int k0 = kb * 32 + hi * 8;
            bf16x8 v;
            #pragma unroll
            for (int j = 0; j < 8; ++j) v[j] = (__bf16)aW1[(k0 + j) * HID + nn];
            aw1f[kb][nt] = v;
        }
    bf16x8 aw2f[2];
    #pragma unroll
    for (int kk = 0; kk < 2; ++kk) {
        const int k0 = (w * 2 + kk) * 32 + hi * 8;
        bf16x8 v;
        #pragma unroll
        for (int j = 0; j < 8; ++j) v[j] = (__bf16)aW2[(k0 + j) * 16 + l15];
        aw2f[kk] = v;
    }
    float4 b1v[4];
    #pragma unroll
    for (int nt = 0; nt < 4; ++nt)
        b1v[nt] = *(const float4*)(&ab1[wcol + nt * 16 + hi * 4]);

    const int m_st = t >> 3;
    const int p_st = t & 7;

    for (int tile = blockIdx.x; tile < ATOM_TILES; tile += ANBLK) {
        const int node0 = tile * 32;
        {
            const float* qr = q + (size_t)(node0 + m_st) * 64 + p_st * 8;
            const float4 a0 = *(const float4*)(qr);
            const float4 a1 = *(const float4*)(qr + 4);
            bf16x8 v;
            v[0] = (__bf16)a0.x; v[1] = (__bf16)a0.y; v[2] = (__bf16)a0.z; v[3] = (__bf16)a0.w;
            v[4] = (__bf16)a1.x; v[5] = (__bf16)a1.y; v[6] = (__bf16)a1.z; v[7] = (__bf16)a1.w;
            *(bf16x8*)(&sm.qs[m_st][p_st * 8]) = v;
            if constexpr (EMIT_QB)
                *(bf16x8*)(qb + (size_t)(node0 + m_st) * 64 + p_st * 8) = v;
        }
        __syncthreads();

        f32x4 acc[2][4];
        #pragma unroll
        for (int mt = 0; mt < 2; ++mt)
            #pragma unroll
            for (int nt = 0; nt < 4; ++nt)
                #pragma unroll
                for (int r = 0; r < 4; ++r)
                    acc[mt][nt][r] = ((const float*)&b1v[nt])[r];

        #pragma unroll
        for (int kb = 0; kb < 2; ++kb)
            #pragma unroll
            for (int mt = 0; mt < 2; ++mt) {
                const bf16x8 bq = *(const bf16x8*)((const char*)&sm.qs[0][0]
                                   + (mt * 16 + l15) * 144 + kb * 64 + hi * 16);
                #pragma unroll
                for (int nt = 0; nt < 4; ++nt)
                    acc[mt][nt] = __builtin_amdgcn_mfma_f32_16x16x32_bf16(
                        aw1f[kb][nt], bq, acc[mt][nt], 0, 0, 0);
            }

        #pragma unroll
        for (int mt = 0; mt < 2; ++mt)
            #pragma unroll
            for (int nt = 0; nt < 4; ++nt) {
                bf16x4 hv;
                #pragma unroll
                for (int r = 0; r < 4; ++r)
                    hv[r] = (__bf16)fmaxf(acc[mt][nt][r], 0.f);
                *(bf16x4*)(&sm.hsE[mt * 16 + l15][wcol + nt * 16 + hi * 4]) = hv;
            }
        __syncthreads();

        f32x4 acc2[2];
        {
            f32x4 z = {0.f, 0.f, 0.f, 0.f};
            acc2[0] = z; acc2[1] = z;
        }
        #pragma unroll
        for (int mt = 0; mt < 2; ++mt)
            #pragma unroll
            for (int kk = 0; kk < 2; ++kk) {
                const int kb = w * 2 + kk;
                const bf16x8 af = *(const bf16x8*)((const char*)&sm.hsE[0][0]
                                   + (mt * 16 + l15) * 528 + kb * 64 + hi * 16);
                acc2[mt] = __builtin_amdgcn_mfma_f32_16x16x32_bf16(
                    af, aw2f[kk], acc2[mt], 0, 0, 0);
            }
        #pragma unroll
        for (int mt = 0; mt < 2; ++mt)
            #pragma unroll
            for (int r = 0; r < 4; ++r)
                sm.red[w][mt][r][lane] = acc2[mt][r];
        __syncthreads();

        {
            const int o  = t & 15;
            const int m0 = t >> 4;
            #pragma unroll
            for (int half = 0; half < 2; ++half) {
                const int m  = m0 + half * 16;
                const int mt = m >> 4, rr = m & 15;
                const int hh = rr >> 2, r = rr & 3;
                float s = ab2[o];
                #pragma unroll
                for (int ww = 0; ww < 4; ++ww) s += sm.red[ww][mt][r][hh * 16 + o];
                const int node = node0 + m;
                if (o < NTYPES) outA[node * NTYPES + o] = s;
                else            outB[node * NCHG + (o - NTYPES)] = s;
            }
        }
        __syncthreads();
    }
}

// ---------------------------------------------------------------------------
// Edge MLP v6: 256 threads (4 waves), 32-edge tiles, 64 hidden/wave.
// ONE barrier per tile:
//  - comb double-buffered (stage t+1 while computing t)
//  - layer-2 K-split slice == wave's own hsE slice (no cross-wave wait)
//  - red double-buffered; epilogue for tile t-1 pipelined into iter t
// W2 k-slice fragments in registers. No setprio (lockstep structure).
// ---------------------------------------------------------------------------
struct __align__(16) ESmem {
    __bf16 comb[2][ETILE][104];   // 13312 B (208 B rows)
    __bf16 hsE[ETILE][264];       // 16896 B (528 B rows)
    float  red[2][4][2][4][64];   // 16384 B
};                                // 46592 B -> 3 blocks/CU

__device__ __forceinline__ void bar_lgkm() {
    asm volatile("s_waitcnt lgkmcnt(0)" ::: "memory");
    __builtin_amdgcn_s_barrier();
}

template<bool USEBF>
__global__ __launch_bounds__(256, 3) void edge_kernel(
    const float* __restrict__ pos, const float* __restrict__ qf,
    const __bf16* __restrict__ qb, const int* __restrict__ pair,
    const float* __restrict__ bW1, const float* __restrict__ bb1,
    const float* __restrict__ bW2, const float* __restrict__ bb2,
    float* __restrict__ outC)
{
    __shared__ ESmem sm;
    const int t    = threadIdx.x;
    const int w    = t >> 6;           // 0..3
    const int lane = t & 63;
    const int l15  = lane & 15;
    const int hi   = lane >> 4;
    const int hid0 = w * 64;           // wave's hidden slice

    // W1^T fragments: this wave's 64 hidden cols
    bf16x8 bw1f[3][4];
    #pragma unroll
    for (int kb = 0; kb < 3; ++kb)
        #pragma unroll
        for (int nt = 0; nt < 4; ++nt) {
            const int nn = hid0 + nt * 16 + l15;
            const int k0 = kb * 32 + hi * 8;
            bf16x8 v;
            #pragma unroll
            for (int j = 0; j < 8; ++j) v[j] = (__bf16)bW1[(k0 + j) * HID + nn];
            bw1f[kb][nt] = v;
        }
    // W2 fragments for this wave's K-slice [hid0, hid0+64)
    bf16x8 w2f[2];
    #pragma unroll
    for (int kk = 0; kk < 2; ++kk) {
        const int k0 = hid0 + kk * 32 + hi * 8;
        bf16x8 v;
        #pragma unroll
        for (int j = 0; j < 8; ++j)
            v[j] = (l15 < NBOND) ? (__bf16)bW2[(k0 + j) * NBOND + l15] : (__bf16)0.f;
        w2f[kk] = v;
    }
    float4 b1v[4];
    #pragma unroll
    for (int nt = 0; nt < 4; ++nt)
        b1v[nt] = *(const float4*)(&bb1[hid0 + nt * 16 + hi * 4]);

    const int e_loc = t >> 3;   // 0..31
    const int p     = t & 7;

    // ---- prologue: gather tile0, stage comb[0], gather tile1 ----
    int tile = blockIdx.x;
    bf16x8 gs, gd;
    float4 fs0, fs1, fd0, fd1;
    float  ps0, ps1, ps2, pd0, pd1, pd2;
    int2 pA = ((const int2*)pair)[(size_t)tile * ETILE + e_loc];
    #define GATHER(pN)                                                            \
        if constexpr (USEBF) {                                                    \
            gs = *(const bf16x8*)(qb + ((unsigned)(pN).x * 64u + (unsigned)(p*8)));\
            gd = *(const bf16x8*)(qb + ((unsigned)(pN).y * 64u + (unsigned)(p*8)));\
        } else {                                                                  \
            fs0 = *(const float4*)(qf + ((unsigned)(pN).x * 64u + (unsigned)(p*8)));     \
            fs1 = *(const float4*)(qf + ((unsigned)(pN).x * 64u + (unsigned)(p*8) + 4u));\
            fd0 = *(const float4*)(qf + ((unsigned)(pN).y * 64u + (unsigned)(p*8)));     \
            fd1 = *(const float4*)(qf + ((unsigned)(pN).y * 64u + (unsigned)(p*8) + 4u));\
        }                                                                         \
        ps0 = pos[(unsigned)(pN).x * 3u];  ps1 = pos[(unsigned)(pN).x * 3u + 1u]; \
        ps2 = pos[(unsigned)(pN).x * 3u + 2u];                                    \
        pd0 = pos[(unsigned)(pN).y * 3u];  pd1 = pos[(unsigned)(pN).y * 3u + 1u]; \
        pd2 = pos[(unsigned)(pN).y * 3u + 2u];

    #define STAGE(buf)                                                            \
        {                                                                         \
            bf16x8 cv;                                                            \
            if constexpr (USEBF) {                                                \
                _Pragma("unroll")                                                 \
                for (int j = 0; j < 8; ++j)                                       \
                    cv[j] = (__bf16)((float)gs[j] + (float)gd[j]);                \
            } else {                                                              \
                cv[0] = (__bf16)(fs0.x + fd0.x); cv[1] = (__bf16)(fs0.y + fd0.y); \
                cv[2] = (__bf16)(fs0.z + fd0.z); cv[3] = (__bf16)(fs0.w + fd0.w); \
                cv[4] = (__bf16)(fs1.x + fd1.x); cv[5] = (__bf16)(fs1.y + fd1.y); \
                cv[6] = (__bf16)(fs1.z + fd1.z); cv[7] = (__bf16)(fs1.w + fd1.w); \
            }                                                                     \
            *(bf16x8*)(&sm.comb[buf][e_loc][p * 8]) = cv;                         \
            const float dx = ps0 - pd0, dy = ps1 - pd1, dz = ps2 - pd2;           \
            const float D  = sqrtf(fmaxf(dx * dx + dy * dy + dz * dz, 1e-8f));    \
            bf16x4 rv;                                                            \
            _Pragma("unroll")                                                     \
            for (int j = 0; j < 4; ++j) {                                         \
                const float mu = (float)(p * 4 + j) * (10.0f / 31.0f);            \
                const float z  = (D - mu) * 3.2f;                                 \
                rv[j] = (__bf16)__expf(-z * z);                                   \
            }                                                                     \
            *(bf16x4*)(&sm.comb[buf][e_loc][64 + p * 4]) = rv;                    \
        }

    GATHER(pA);
    {
        const int tn = tile + ENBLK;
        pA = ((const int2*)pair)[(tn < ETILES ? (size_t)tn * ETILE : 0) + e_loc];
    }
    STAGE(0);
    GATHER(pA);
    {
        const int tn = tile + 2 * ENBLK;
        pA = ((const int2*)pair)[(tn < ETILES ? (size_t)tn * ETILE : 0) + e_loc];
    }
    bar_lgkm();

    int cur = 0;
    int e0_prev = -1;

    for (; tile < ETILES; tile += ENBLK) {
        const int e0 = tile * ETILE;

        // 1. epilogue for previous tile (red[cur^1] ready after last barrier)
        if (e0_prev >= 0 && t < 160) {
            const int m = t / 5, o = t % 5;
            const int mt = m >> 4, rr = m & 15;
            const int hh = rr >> 2, r = rr & 3;
            float s = bb2[o];
            #pragma unroll
            for (int ww = 0; ww < 4; ++ww)
                s += sm.red[cur ^ 1][ww][mt][r][hh * 16 + o];
            outC[(size_t)(e0_prev + m) * NBOND + o] = s;
        }

        // 2. stage comb[cur^1] for tile+ENBLK from in-flight gathers
        STAGE(cur ^ 1);

        // 3. issue gathers for tile+2*ENBLK; load pair for tile+3*ENBLK
        GATHER(pA);
        {
            const int tn = tile + 3 * ENBLK;
            pA = ((const int2*)pair)[(tn < ETILES ? (size_t)tn * ETILE : 0) + e_loc];
        }

        // 4. layer 1 on comb[cur]: wave = 64 hidden x 32 edges
        f32x4 acc[2][4];
        #pragma unroll
        for (int mt = 0; mt < 2; ++mt)
            #pragma unroll
            for (int nt = 0; nt < 4; ++nt)
                #pragma unroll
                for (int r = 0; r < 4; ++r)
                    acc[mt][nt][r] = ((const float*)&b1v[nt])[r];

        #pragma unroll
        for (int kb = 0; kb < 3; ++kb)
            #pragma unroll
            for (int mt = 0; mt < 2; ++mt) {
                const bf16x8 bf = *(const bf16x8*)((const char*)&sm.comb[cur][0][0]
                                   + (mt * 16 + l15) * 208 + kb * 64 + hi * 16);
                #pragma unroll
                for (int nt = 0; nt < 4; ++nt)
                    acc[mt][nt] = __builtin_amdgcn_mfma_f32_16x16x32_bf16(
                        bw1f[kb][nt], bf, acc[mt][nt], 0, 0, 0);
            }
        // relu -> hsE[edge][hid0..hid0+64)  (own slice; no barrier needed)
        #pragma unroll
        for (int mt = 0; mt < 2; ++mt)
            #pragma unroll
            for (int nt = 0; nt < 4; ++nt) {
                bf16x4 hv;
                #pragma unroll
                for (int r = 0; r < 4; ++r)
                    hv[r] = (__bf16)fmaxf(acc[mt][nt][r], 0.f);
                *(bf16x4*)((char*)&sm.hsE[0][0]
                           + (mt * 16 + l15) * 528 + (hid0 + nt * 16 + hi * 4) * 2) = hv;
            }

        // 5. layer 2: wave's own K-slice; partials -> red[cur]
        {
            f32x4 acc2[2];
            {
                f32x4 z = {0.f, 0.f, 0.f, 0.f};
                acc2[0] = z; acc2[1] = z;
            }
            #pragma unroll
            for (int mt = 0; mt < 2; ++mt)
                #pragma unroll
                for (int kk = 0; kk < 2; ++kk) {
                    const bf16x8 af = *(const bf16x8*)((const char*)&sm.hsE[0][0]
                                       + (mt * 16 + l15) * 528
                                       + (hid0 + kk * 32 + hi * 8) * 2);
                    acc2[mt] = __builtin_amdgcn_mfma_f32_16x16x32_bf16(
                        af, w2f[kk], acc2[mt], 0, 0, 0);
                }
            #pragma unroll
            for (int mt = 0; mt < 2; ++mt)
                #pragma unroll
                for (int r = 0; r < 4; ++r)
                    sm.red[cur][w][mt][r][lane] = acc2[mt][r];
        }

        e0_prev = e0;
        bar_lgkm();     // single barrier: comb[cur^1] + red[cur] now visible
        cur ^= 1;
    }

    // final epilogue (red[cur^1] = last tile's partials, visible after last bar)
    if (e0_prev >= 0 && t < 160) {
        const int m = t / 5, o = t % 5;
        const int mt = m >> 4, rr = m & 15;
        const int hh = rr >> 2, r = rr & 3;
        float s = bb2[o];
        #pragma unroll
        for (int ww = 0; ww < 4; ++ww)
            s += sm.red[cur ^ 1][ww][mt][r][hh * 16 + o];
        outC[(size_t)(e0_prev + m) * NBOND + o] = s;
    }
    #undef GATHER
    #undef STAGE
}

// ---------------------------------------------------------------------------
extern "C" void kernel_launch(void* const* d_in, const int* in_sizes, int n_in,
                              void* d_out, int out_size, void* d_ws, size_t ws_size,
                              hipStream_t stream)
{
    const float* pos = (const float*)d_in[0];
    const float* q   = (const float*)d_in[1];
    const int*   pair= (const int*)  d_in[2];
    const float* aW1 = (const float*)d_in[3];
    const float* ab1 = (const float*)d_in[4];
    const float* aW2 = (const float*)d_in[5];
    const float* ab2 = (const float*)d_in[6];
    const float* bW1 = (const float*)d_in[7];
    const float* bb1 = (const float*)d_in[8];
    const float* bW2 = (const float*)d_in[9];
    const float* bb2 = (const float*)d_in[10];

    float* out  = (float*)d_out;
    float* outA = out;
    float* outB = out + (size_t)N_NODES * NTYPES;
    float* outC = out + (size_t)N_NODES * (NTYPES + NCHG);

    const size_t qb_bytes = (size_t)N_NODES * LATENT * sizeof(__bf16);
    const bool use_bf = (ws_size >= qb_bytes);
    __bf16* qb = (__bf16*)d_ws;

    if (use_bf)
        hipLaunchKernelGGL(atom_kernel<true>, dim3(ANBLK), dim3(256), 0, stream,
                           q, aW1, ab1, aW2, ab2, outA, outB, qb);
    else
        hipLaunchKernelGGL(atom_kernel<false>, dim3(ANBLK), dim3(256), 0, stream,
                           q, aW1, ab1, aW2, ab2, outA, outB, qb);

    if (use_bf)
        hipLaunchKernelGGL(edge_kernel<true>, dim3(ENBLK), dim3(256), 0, stream,
                           pos, q, qb, pair, bW1, bb1, bW2, bb2, outC);
    else
        hipLaunchKernelGGL(edge_kernel<false>, dim3(ENBLK), dim3(256), 0, stream,
                           pos, q, qb, pair, bW1, bb1, bW2, bb2, outC);
}